// Round 8
// baseline (66.041 us; speedup 1.0000x reference)
//
#include <hip/hip_runtime.h>
#include <math.h>

// NoisyTopKRouter via f16 2-limb (Markidis) 3-pass MFMA.
// Round 8: round-7 structure with the PSTR overflow fixed (PSTR 17 -> 36)
// and a deterministic in-LDS tree reduction over the 8 split-K partials.
// Wave = 32 tokens x 128 experts over a 256-K slice; barrier-free main loop.
// Grid 512, 512 threads (8 waves), 2 blocks/CU.

typedef _Float16 f16;
typedef _Float16 f16x8 __attribute__((ext_vector_type(8)));
typedef float    f32x4 __attribute__((ext_vector_type(4)));

#define NEMBD 2048
#define NEXP  64
#define TOKB  32              // tokens per block
#define PSTR  36              // token stride in partial tile (16B-aligned rows)
#define PSLC  (128 * PSTR)    // floats per partial slice (4608)
#define WSCALE 64.0f
#define INV_WSCALE 0.015625f

union F4H8 { float4 f; f16x8 h; };

__device__ __forceinline__ f16x8 ld16h(const f16* p) {
    F4H8 u; u.f = *(const float4*)p; return u.h;
}

// ---------- kernel 0: W -> transposed, x64-scaled f16 limbs ----------
// wt layout per limb: [chunk 64][n 128][k 32] f16 (n: 0..63 route, 64..127 noise)
__global__ __launch_bounds__(256) void build_wt(
    const float* __restrict__ Wr, const float* __restrict__ Wn,
    f16* __restrict__ wt_hi, f16* __restrict__ wt_lo)
{
    __shared__ float ws[32][129];
    const int c = blockIdx.x, t = threadIdx.x;
    const int k0 = c * 32;
    {
        const int k  = t >> 3;
        const int n8 = (t & 7) << 3;
        const float* s0 = Wr + (size_t)(k0 + k) * NEXP + n8;
        const float* s1 = Wn + (size_t)(k0 + k) * NEXP + n8;
        #pragma unroll
        for (int j = 0; j < 8; ++j) ws[k][n8 + j] = s0[j];
        #pragma unroll
        for (int j = 0; j < 8; ++j) ws[k][64 + n8 + j] = s1[j];
    }
    __syncthreads();
    {
        const int n  = t >> 1;           // 0..127
        const int kh = (t & 1) << 4;     // 0 or 16
        f16x8 hv0, hv1, lv0, lv1;
        #pragma unroll
        for (int j = 0; j < 8; ++j) {
            const float v = ws[kh + j][n] * WSCALE;
            const f16 h = (f16)v;
            hv0[j] = h; lv0[j] = (f16)(v - (float)h);
        }
        #pragma unroll
        for (int j = 0; j < 8; ++j) {
            const float v = ws[kh + 8 + j][n] * WSCALE;
            const f16 h = (f16)v;
            hv1[j] = h; lv1[j] = (f16)(v - (float)h);
        }
        const size_t base = ((size_t)c * 128 + n) * 32 + kh;
        *(f16x8*)(wt_hi + base)     = hv0;
        *(f16x8*)(wt_hi + base + 8) = hv1;
        *(f16x8*)(wt_lo + base)     = lv0;
        *(f16x8*)(wt_lo + base + 8) = lv1;
    }
}

// ---------- kernel 1: fused MFMA router, split-K TLP ----------
// 512 threads = 8 waves; wave w handles all 32 tokens x 128 cols over
// K slice [w*256, (w+1)*256). No main-loop barriers.
__global__ __launch_bounds__(512, 4) void router_fused6(
    const float* __restrict__ x, const float* __restrict__ eps,
    const f16* __restrict__ wt_hi, const f16* __restrict__ wt_lo,
    const float* __restrict__ br, const float* __restrict__ bn,
    float* __restrict__ out_r, float* __restrict__ out_idx)
{
    // P[4][128][PSTR] f32 partial slices (73,728 B) + TK[4][32]
    __shared__ __align__(16) float P[4 * PSLC];
    __shared__ float TK[4 * TOKB];

    const int tid  = threadIdx.x;
    const int lane = tid & 63;
    const int w    = tid >> 6;           // K-slice 0..7
    const int m0   = blockIdx.x * TOKB;

    const int row16 = lane & 15;
    const int kgrp  = (lane >> 4) << 3;  // 0,8,16,24

    // A: rows row16 (frag 0) and row16+16 (frag 1), K base = w*256
    const float* asrc0 = x + (size_t)(m0 + row16) * NEMBD + w * 256 + kgrp;
    const float* asrc1 = asrc0 + (size_t)16 * NEMBD;

    // B: col frag f -> cols f*16+row16; chunk g = w*8 + c
    const int bofs = row16 * 32 + kgrp;

    f32x4 acc[2][8];
    #pragma unroll
    for (int i = 0; i < 2; ++i)
        #pragma unroll
        for (int f = 0; f < 8; ++f) acc[i][f] = (f32x4){0.f, 0.f, 0.f, 0.f};

#define SPLIT8(A0, A1, ah, al) do { \
    const float av[8] = {A0.x, A0.y, A0.z, A0.w, A1.x, A1.y, A1.z, A1.w}; \
    _Pragma("unroll") \
    for (int j = 0; j < 8; ++j) { \
        const f16 h = (f16)av[j]; ah[j] = h; al[j] = (f16)(av[j] - (float)h); } \
    } while (0)

    for (int c = 0; c < 8; ++c) {
        const int g = (w << 3) + c;
        const size_t cb = (size_t)g * 4096;
        const f16* bh_base = wt_hi + cb + bofs;
        const f16* bl_base = wt_lo + cb + bofs;

        const float4 a00 = *(const float4*)(asrc0 + c * 32);
        const float4 a01 = *(const float4*)(asrc0 + c * 32 + 4);
        const float4 a10 = *(const float4*)(asrc1 + c * 32);
        const float4 a11 = *(const float4*)(asrc1 + c * 32 + 4);
        f16x8 ah0, al0, ah1, al1;
        SPLIT8(a00, a01, ah0, al0);
        SPLIT8(a10, a11, ah1, al1);

        #pragma unroll
        for (int fg = 0; fg < 4; ++fg) {
            const f16x8 bh0 = ld16h(bh_base + (2 * fg) * 512);
            const f16x8 bl0 = ld16h(bl_base + (2 * fg) * 512);
            const f16x8 bh1 = ld16h(bh_base + (2 * fg + 1) * 512);
            const f16x8 bl1 = ld16h(bl_base + (2 * fg + 1) * 512);
            acc[0][2*fg]   = __builtin_amdgcn_mfma_f32_16x16x32_f16(ah0, bh0, acc[0][2*fg],   0, 0, 0);
            acc[0][2*fg]   = __builtin_amdgcn_mfma_f32_16x16x32_f16(al0, bh0, acc[0][2*fg],   0, 0, 0);
            acc[0][2*fg]   = __builtin_amdgcn_mfma_f32_16x16x32_f16(ah0, bl0, acc[0][2*fg],   0, 0, 0);
            acc[1][2*fg]   = __builtin_amdgcn_mfma_f32_16x16x32_f16(ah1, bh0, acc[1][2*fg],   0, 0, 0);
            acc[1][2*fg]   = __builtin_amdgcn_mfma_f32_16x16x32_f16(al1, bh0, acc[1][2*fg],   0, 0, 0);
            acc[1][2*fg]   = __builtin_amdgcn_mfma_f32_16x16x32_f16(ah1, bl0, acc[1][2*fg],   0, 0, 0);
            acc[0][2*fg+1] = __builtin_amdgcn_mfma_f32_16x16x32_f16(ah0, bh1, acc[0][2*fg+1], 0, 0, 0);
            acc[0][2*fg+1] = __builtin_amdgcn_mfma_f32_16x16x32_f16(al0, bh1, acc[0][2*fg+1], 0, 0, 0);
            acc[0][2*fg+1] = __builtin_amdgcn_mfma_f32_16x16x32_f16(ah0, bl1, acc[0][2*fg+1], 0, 0, 0);
            acc[1][2*fg+1] = __builtin_amdgcn_mfma_f32_16x16x32_f16(ah1, bh1, acc[1][2*fg+1], 0, 0, 0);
            acc[1][2*fg+1] = __builtin_amdgcn_mfma_f32_16x16x32_f16(al1, bh1, acc[1][2*fg+1], 0, 0, 0);
            acc[1][2*fg+1] = __builtin_amdgcn_mfma_f32_16x16x32_f16(ah1, bl1, acc[1][2*fg+1], 0, 0, 0);
        }
    }
#undef SPLIT8

    // ---- deterministic split-K tree reduction in LDS ----
    const int tokb = (lane >> 4) << 2;

    // stage 1: waves 4..7 write their partials to slice w-4
    if (w >= 4) {
        float* Pw = P + (w - 4) * PSLC;
        #pragma unroll
        for (int f = 0; f < 8; ++f) {
            const int col = f * 16 + row16;
            #pragma unroll
            for (int i = 0; i < 2; ++i) {
                float4 v;
                v.x = acc[i][f][0] * INV_WSCALE;
                v.y = acc[i][f][1] * INV_WSCALE;
                v.z = acc[i][f][2] * INV_WSCALE;
                v.w = acc[i][f][3] * INV_WSCALE;
                *(float4*)(Pw + col * PSTR + i * 16 + tokb) = v;
            }
        }
    }
    __syncthreads();

    // stage 2: waves 0..3 add their partials into slice w
    if (w < 4) {
        float* Pw = P + w * PSLC;
        #pragma unroll
        for (int f = 0; f < 8; ++f) {
            const int col = f * 16 + row16;
            #pragma unroll
            for (int i = 0; i < 2; ++i) {
                float* dst = Pw + col * PSTR + i * 16 + tokb;
                float4 d = *(float4*)dst;
                d.x += acc[i][f][0] * INV_WSCALE;
                d.y += acc[i][f][1] * INV_WSCALE;
                d.z += acc[i][f][2] * INV_WSCALE;
                d.w += acc[i][f][3] * INV_WSCALE;
                *(float4*)dst = d;
            }
        }
    }
    __syncthreads();

    // stage 3a: P[0] += P[2], P[1] += P[3]  (2048 float4-chunks, 4/thread)
    #pragma unroll
    for (int k = 0; k < 4; ++k) {
        const int ch  = tid + k * 512;        // 0..2047
        const int s   = ch >> 10;             // 0 or 1
        const int r   = ch & 1023;
        const int col = r >> 3;
        const int tkc = (r & 7) << 2;
        float* dst = P + s * PSLC + col * PSTR + tkc;
        const float* src = P + (s + 2) * PSLC + col * PSTR + tkc;
        float4 d = *(float4*)dst;
        const float4 sv = *(const float4*)src;
        d.x += sv.x; d.y += sv.y; d.z += sv.z; d.w += sv.w;
        *(float4*)dst = d;
    }
    __syncthreads();

    // stage 3b: P[0] += P[1]  (1024 chunks, 2/thread)
    #pragma unroll
    for (int k = 0; k < 2; ++k) {
        const int r   = tid + k * 512;        // 0..1023
        const int col = r >> 3;
        const int tkc = (r & 7) << 2;
        float* dst = P + col * PSTR + tkc;
        const float* src = P + PSLC + col * PSTR + tkc;
        float4 d = *(float4*)dst;
        const float4 sv = *(const float4*)src;
        d.x += sv.x; d.y += sv.y; d.z += sv.z; d.w += sv.w;
        *(float4*)dst = d;
    }
    __syncthreads();

    // ---- bias + noise + top-2: 4 lanes per token ----
    if (tid < 128) {
        const int t = tid >> 2;          // token 0..31
        const int q = tid & 3;           // expert quarter
        const float* ep = eps + (size_t)(m0 + t) * NEXP;
        float v1 = -1e30f, v2 = -1e30f;
        int i1 = 0, i2 = 0;
        for (int j = 0; j < 16; ++j) {
            const int e = q * 16 + j;
            const float r  = br[e] + P[e * PSTR + t];
            const float nr = bn[e] + P[(NEXP + e) * PSTR + t];
            const float sp = fmaxf(nr, 0.f) + log1pf(expf(-fabsf(nr)));
            const float noisy = fmaf(ep[e], sp, r);
            if (noisy > v1) { v2 = v1; i2 = i1; v1 = noisy; i1 = e; }
            else if (noisy > v2) { v2 = noisy; i2 = e; }
        }
        // merge across the 4 lanes of this token (prefer lower-index half on ties)
        #pragma unroll
        for (int s = 0; s < 2; ++s) {
            const int dist = 1 << s;
            const float ov1 = __shfl_xor(v1, dist);
            const float ov2 = __shfl_xor(v2, dist);
            const int   oi1 = __shfl_xor(i1, dist);
            const int   oi2 = __shfl_xor(i2, dist);
            const int h = (q >> s) & 1;  // 1 => I'm the upper-index half
            float a1, a2, bb1, bb2; int ai1, ai2, bj1, bj2;
            if (h) { a1 = ov1; a2 = ov2; ai1 = oi1; ai2 = oi2; bb1 = v1;  bb2 = v2;  bj1 = i1;  bj2 = i2; }
            else   { a1 = v1;  a2 = v2;  ai1 = i1;  ai2 = i2;  bb1 = ov1; bb2 = ov2; bj1 = oi1; bj2 = oi2; }
            if (bb1 > a1) {
                v1 = bb1; i1 = bj1;
                if (a1 >= bb2) { v2 = a1; i2 = ai1; } else { v2 = bb2; i2 = bj2; }
            } else {
                v1 = a1; i1 = ai1;
                if (bb1 > a2) { v2 = bb1; i2 = bj1; } else { v2 = a2; i2 = ai2; }
            }
        }
        if (q == 0) {
            const float e2 = expf(v2 - v1);
            const float p1 = 1.f / (1.f + e2);
            TK[0 * TOKB + t] = p1;
            TK[1 * TOKB + t] = e2 * p1;
            TK[2 * TOKB + t] = (float)i1;
            TK[3 * TOKB + t] = (float)i2;
        }
    }
    __syncthreads();

    // ---- write r_out coalesced (4 floats/thread) ----
    {
        const int t  = tid >> 4;             // 0..31
        const int c4 = (tid & 15) << 2;      // 0..60
        const float p1 = TK[t], p2 = TK[TOKB + t];
        const int i1 = (int)TK[2 * TOKB + t], i2 = (int)TK[3 * TOKB + t];
        float buf[4];
        #pragma unroll
        for (int jj = 0; jj < 4; ++jj) {
            const int e = c4 + jj;
            buf[jj] = (e == i1) ? p1 : (e == i2) ? p2 : 0.f;
        }
        *(float4*)(out_r + (size_t)(m0 + t) * NEXP + c4) = *(float4*)buf;
    }
    if (tid < TOKB) {
        float2 v = make_float2(TK[2 * TOKB + tid], TK[3 * TOKB + tid]);
        *(float2*)(out_idx + (size_t)(m0 + tid) * 2) = v;
    }
}

// ---------- fallback: fused f32 kernel (insurance only) ----------
__global__ __launch_bounds__(256) void router_fused_f32(
    const float* __restrict__ x, const float* __restrict__ eps,
    const float* __restrict__ Wr, const float* __restrict__ br,
    const float* __restrict__ Wn, const float* __restrict__ bn,
    float* __restrict__ out_r, float* __restrict__ out_idx)
{
    __shared__ float xs[32][64];
    __shared__ float ws2[32][128];
    __shared__ float lg[128][64];
    __shared__ float tk[4][64];
    const int tid = threadIdx.x;
    const int tx = tid & 15, ty = tid >> 4;
    const int m0 = blockIdx.x * 64;
    float acc[4][8];
    #pragma unroll
    for (int i = 0; i < 4; ++i)
        #pragma unroll
        for (int j = 0; j < 8; ++j) acc[i][j] = 0.f;
    for (int kc = 0; kc < NEMBD; kc += 32) {
        {
            const int tm = tid >> 2, kk = (tid & 3) << 3;
            const float* src = x + (size_t)(m0 + tm) * NEMBD + kc + kk;
            const float4 a = *(const float4*)(src);
            const float4 b = *(const float4*)(src + 4);
            xs[kk+0][tm]=a.x; xs[kk+1][tm]=a.y; xs[kk+2][tm]=a.z; xs[kk+3][tm]=a.w;
            xs[kk+4][tm]=b.x; xs[kk+5][tm]=b.y; xs[kk+6][tm]=b.z; xs[kk+7][tm]=b.w;
        }
        {
            const int kr = tid >> 3, q = tid & 7;
            const float* src = (q < 4)
                ? (Wr + (size_t)(kc + kr) * NEXP + (q << 4))
                : (Wn + (size_t)(kc + kr) * NEXP + ((q - 4) << 4));
            float* dst = &ws2[kr][q << 4];
            #pragma unroll
            for (int j = 0; j < 16; ++j) dst[j] = src[j];
        }
        __syncthreads();
        #pragma unroll
        for (int k = 0; k < 32; ++k) {
            const float4 xv = *(const float4*)&xs[k][ty << 2];
            const float4 wa = *(const float4*)&ws2[k][tx << 3];
            const float4 wb = *(const float4*)&ws2[k][(tx << 3) + 4];
            const float xr[4] = {xv.x, xv.y, xv.z, xv.w};
            const float wcx[8] = {wa.x, wa.y, wa.z, wa.w, wb.x, wb.y, wb.z, wb.w};
            #pragma unroll
            for (int i = 0; i < 4; ++i)
                #pragma unroll
                for (int j = 0; j < 8; ++j)
                    acc[i][j] = fmaf(xr[i], wcx[j], acc[i][j]);
        }
        __syncthreads();
    }
    {
        const int n0 = tx << 3;
        #pragma unroll
        for (int j = 0; j < 8; ++j) {
            const int n = n0 + j;
            const float b = (n < NEXP) ? br[n] : bn[n - NEXP];
            #pragma unroll
            for (int i = 0; i < 4; ++i)
                lg[n][(ty << 2) + i] = acc[i][j] + b;
        }
    }
    __syncthreads();
    if (tid < 64) {
        const int t = tid;
        const float* ep = eps + (size_t)(m0 + t) * NEXP;
        float v1 = -1e30f, v2 = -1e30f; int i1 = 0, i2 = 0;
        for (int e = 0; e < NEXP; ++e) {
            const float r = lg[e][t], nr = lg[NEXP + e][t];
            const float sp = fmaxf(nr, 0.f) + log1pf(expf(-fabsf(nr)));
            const float noisy = fmaf(ep[e], sp, r);
            if (noisy > v1) { v2=v1; i2=i1; v1=noisy; i1=e; }
            else if (noisy > v2) { v2=noisy; i2=e; }
        }
        const float e2 = expf(v2 - v1);
        const float p1 = 1.f / (1.f + e2);
        tk[0][t]=p1; tk[1][t]=e2*p1; tk[2][t]=(float)i1; tk[3][t]=(float)i2;
    }
    __syncthreads();
    {
        const int t = tid >> 2, c = tid & 3;
        const float p1 = tk[0][t], p2 = tk[1][t];
        const int i1 = (int)tk[2][t], i2 = (int)tk[3][t];
        float buf[16];
        #pragma unroll
        for (int j = 0; j < 16; ++j) {
            const int e = (c << 4) + j;
            buf[j] = (e == i1) ? p1 : (e == i2) ? p2 : 0.f;
        }
        float* dst = out_r + (size_t)(m0 + t) * NEXP + (c << 4);
        *(float4*)(dst+0)=*(float4*)(buf+0); *(float4*)(dst+4)=*(float4*)(buf+4);
        *(float4*)(dst+8)=*(float4*)(buf+8); *(float4*)(dst+12)=*(float4*)(buf+12);
    }
    if (tid < 64) {
        float2 v = make_float2(tk[2][tid], tk[3][tid]);
        *(float2*)(out_idx + (size_t)(m0 + tid) * 2) = v;
    }
}

extern "C" void kernel_launch(void* const* d_in, const int* in_sizes, int n_in,
                              void* d_out, int out_size, void* d_ws, size_t ws_size,
                              hipStream_t stream) {
    const float* x  = (const float*)d_in[0];
    const float* ep = (const float*)d_in[1];
    const float* Wr = (const float*)d_in[2];
    const float* br = (const float*)d_in[3];
    const float* Wn = (const float*)d_in[4];
    const float* bn = (const float*)d_in[5];

    const int T = in_sizes[1] / NEXP;
    float* out_r   = (float*)d_out;
    float* out_idx = (float*)d_out + (size_t)T * NEXP;

    const size_t limb = (size_t)128 * NEMBD * sizeof(f16);   // 512 KB
    if (ws_size >= 2 * limb) {
        f16* wt_hi = (f16*)d_ws;
        f16* wt_lo = wt_hi + (size_t)128 * NEMBD;
        build_wt<<<64, 256, 0, stream>>>(Wr, Wn, wt_hi, wt_lo);
        router_fused6<<<T / TOKB, 512, 0, stream>>>(
            x, ep, wt_hi, wt_lo, br, bn, out_r, out_idx);
    } else {
        router_fused_f32<<<T / 64, 256, 0, stream>>>(
            x, ep, Wr, br, Wn, bn, out_r, out_idx);
    }
}